// Round 6
// baseline (143.323 us; speedup 1.0000x reference)
//
#include <hip/hip_runtime.h>
#include <stdint.h>

// ROI max pooling, matching the JAX reference:
//   img:  (1, 200, 200, 512) fp32, NHWC
//   rois: (1, 128, 4) fp32 as (x, y, w, h) in feature-map pixels
//   pool: 7  ->  out: (1, 128, 7, 7, 512) fp32
//
// Bin boundaries replicate  int(x + k*(w/P))  in strict IEEE fp32
// (separate div/mul/add, no FMA contraction) -> bit-exact pixel sets.
//
// R6: register-MLP is compiler-defeated (R2/R4/R5 all compile to VGPR=44,
// ~3 loads in flight, 3.1 TB/s fill). Switch to async global->LDS DMA
// (__builtin_amdgcn_global_load_lds, width 16): fire-and-forget issue,
// vmcnt-tracked, zero VGPR result pressure. Each wave stages ITS OWN half
// of each pixel into a private LDS region -> no __syncthreads anywhere,
// no barrier vmcnt(0) drain. 8-pixel chunks, double-buffered:
// issue chunk c+1, s_waitcnt vmcnt(8) (= chunk c complete), consume chunk c.
// Tail clamp-walks onto the last pixel (max is idempotent).

#define IMG_H 200
#define IMG_W 200
#define IMG_C 512
#define POOL 7
#define NROI 128
#define CHUNK 8   // pixels per buffer

#define AS1(p) ((const __attribute__((address_space(1))) void*)(p))
#define AS3(p) ((__attribute__((address_space(3))) void*)(p))

__device__ __forceinline__ float4 max4(float4 a, float4 b) {
    return make_float4(fmaxf(a.x, b.x), fmaxf(a.y, b.y),
                       fmaxf(a.z, b.z), fmaxf(a.w, b.w));
}

__global__ __launch_bounds__(128) void roi_pool_kernel(
    const float* __restrict__ img,
    const float* __restrict__ rois,
    float* __restrict__ out)
{
    // [wave(2)][buf(2)][slot(CHUNK)][lane(64) x float4] = 32 KB
    __shared__ float lds[2 * 2 * CHUNK * 64 * 4];

    const int tid  = threadIdx.x;
    const int wv   = tid >> 6;
    const int lane = tid & 63;

    const int bin = blockIdx.x % (POOL * POOL);
    const int roi = blockIdx.x / (POOL * POOL);
    const int jy = bin / POOL;
    const int ix = bin % POOL;

    const float rx = rois[roi * 4 + 0];
    const float ry = rois[roi * 4 + 1];
    const float rw = rois[roi * 4 + 2];
    const float rh = rois[roi * 4 + 3];

    // Strict fp32, no contraction: s = w/P; b[k] = int(x + k*s)
    const float sx = __fdiv_rn(rw, 7.0f);
    const float sy = __fdiv_rn(rh, 7.0f);
    const int x1 = (int)__fadd_rn(rx, __fmul_rn((float)ix,       sx));
    const int x2 = (int)__fadd_rn(rx, __fmul_rn((float)(ix + 1), sx));
    const int y1 = (int)__fadd_rn(ry, __fmul_rn((float)jy,       sy));
    const int y2 = (int)__fadd_rn(ry, __fmul_rn((float)(jy + 1), sy));

    const int nx = x2 - x1;              // >= 1 by problem construction
    const int ny = y2 - y1;
    const int n  = nx * ny;
    const int nchunks = (n + CHUNK - 1) / CHUNK;

    // Thread owns float4 slot `tid` of each pixel (16 B); wave wv covers
    // byte range [wv*1024, wv*1024+1024) of each 2 KB pixel.
    const char* gbase = (const char*)img + (size_t)tid * 16;
    float* ldsw = lds + wv * (2 * CHUNK * 256);   // per-wave region (16 KB)

    // Wave-uniform pixel walker; after the last pixel it sticks there, so
    // tail slots re-stage the last pixel (harmless for max).
    int px = 0, py = 0;

    auto issue_chunk = [&](int buf) {
        float* lb = ldsw + buf * (CHUNK * 256);
        #pragma unroll
        for (int s = 0; s < CHUNK; ++s) {
            const char* gp = gbase +
                (size_t)((y1 + py) * IMG_W + (x1 + px)) * (IMG_C * 4);
            __builtin_amdgcn_global_load_lds(AS1(gp), AS3(lb + s * 256), 16, 0, 0);
            if (++px == nx) { px = 0; if (++py == ny) { py = ny - 1; px = nx - 1; } }
        }
    };

    issue_chunk(0);

    float4 m0 = make_float4(-INFINITY, -INFINITY, -INFINITY, -INFINITY);
    float4 m1 = m0;

    for (int c = 0; c < nchunks; ++c) {
        const int buf = c & 1;
        const bool more = (c + 1 < nchunks);
        if (more) {
            issue_chunk(buf ^ 1);
            __builtin_amdgcn_s_waitcnt(0x0F78);   // vmcnt(8): chunk c done
        } else {
            __builtin_amdgcn_s_waitcnt(0x0F70);   // vmcnt(0)
        }
        __builtin_amdgcn_sched_barrier(0);

        const float* lb = ldsw + buf * (CHUNK * 256) + lane * 4;
        #pragma unroll
        for (int s = 0; s < CHUNK; s += 2) {
            float4 v0 = *(const float4*)(lb + (s + 0) * 256);
            float4 v1 = *(const float4*)(lb + (s + 1) * 256);
            m0 = max4(m0, v0);
            m1 = max4(m1, v1);
        }
        __builtin_amdgcn_sched_barrier(0);
    }
    m0 = max4(m0, m1);

    float4* __restrict__ out4 = (float4*)out;
    out4[((size_t)(roi * (POOL * POOL) + bin)) * (IMG_C / 4) + tid] = m0;
}

extern "C" void kernel_launch(void* const* d_in, const int* in_sizes, int n_in,
                              void* d_out, int out_size, void* d_ws, size_t ws_size,
                              hipStream_t stream) {
    (void)in_sizes; (void)n_in; (void)d_ws; (void)ws_size; (void)out_size;
    const float* img  = (const float*)d_in[0];
    const float* rois = (const float*)d_in[1];
    float* out = (float*)d_out;

    dim3 grid(NROI * POOL * POOL);
    dim3 block(128);
    roi_pool_kernel<<<grid, block, 0, stream>>>(img, rois, out);
}